// Round 1
// baseline (581.700 us; speedup 1.0000x reference)
//
#include <hip/hip_runtime.h>
#include <hip/hip_bf16.h>
#include <math.h>

// Problem constants (fixed by the reference): B=16, S=2048, D=1024, HD=64
constexpr int Bsz  = 16;
constexpr int Seq  = 2048;
constexpr int Din  = 1024;
constexpr int Hd   = 64;
constexpr int Rows = Bsz * Seq;  // 32768 tokens

// ---------------------------------------------------------------------------
// Kernel 1: QKV projection.  C[m][n] = sum_k X[m][k] * W[k][n] + b[n]
// Tiled fp32 GEMM: 64x64 block tile, 16-wide k-chunks, 4x4 per-thread tile.
// grid = (Rows/64, 3), block = 256.  blockIdx.y selects Wq/Wk/Wv.
// ---------------------------------------------------------------------------
__global__ __launch_bounds__(256) void qkv_kernel(
    const float* __restrict__ x,
    const float* __restrict__ Wq, const float* __restrict__ bq,
    const float* __restrict__ Wk, const float* __restrict__ bk,
    const float* __restrict__ Wv, const float* __restrict__ bv,
    float* __restrict__ qkv)   // [3][Rows][Hd]
{
    const float* W;
    const float* bias;
    if (blockIdx.y == 0)      { W = Wq; bias = bq; }
    else if (blockIdx.y == 1) { W = Wk; bias = bk; }
    else                      { W = Wv; bias = bv; }
    float* outp = qkv + (size_t)blockIdx.y * Rows * Hd;

    // Xs transposed: Xs[k][m] so the inner loop reads contiguous float4 in m.
    __shared__ float Xs[16][64 + 4];
    __shared__ float Ws[16][64 + 4];

    const int tid = threadIdx.x;
    const int tx  = tid % 16;         // n-tile  (cols tx*4 .. tx*4+3)
    const int ty  = tid / 16;         // m-tile  (rows ty*4 .. ty*4+3)
    const int m0  = blockIdx.x * 64;

    float acc[4][4] = {};

    for (int kk = 0; kk < Din; kk += 16) {
        // Stage X tile (64 rows x 16 k), transposed into Xs[k][m]
        {
            const int r  = tid / 4;          // 0..63 row
            const int c0 = (tid % 4) * 4;    // 0,4,8,12
            const float4 xv = *(const float4*)(x + (size_t)(m0 + r) * Din + kk + c0);
            Xs[c0 + 0][r] = xv.x;
            Xs[c0 + 1][r] = xv.y;
            Xs[c0 + 2][r] = xv.z;
            Xs[c0 + 3][r] = xv.w;
        }
        // Stage W tile (16 k x 64 n), straight
        {
            const int r  = tid / 16;         // 0..15
            const int c0 = (tid % 16) * 4;   // 0..60
            *(float4*)&Ws[r][c0] = *(const float4*)(W + (size_t)(kk + r) * Hd + c0);
        }
        __syncthreads();

        #pragma unroll
        for (int k = 0; k < 16; ++k) {
            const float4 a = *(const float4*)&Xs[k][ty * 4];
            const float4 b = *(const float4*)&Ws[k][tx * 4];
            acc[0][0] += a.x * b.x; acc[0][1] += a.x * b.y; acc[0][2] += a.x * b.z; acc[0][3] += a.x * b.w;
            acc[1][0] += a.y * b.x; acc[1][1] += a.y * b.y; acc[1][2] += a.y * b.z; acc[1][3] += a.y * b.w;
            acc[2][0] += a.z * b.x; acc[2][1] += a.z * b.y; acc[2][2] += a.z * b.z; acc[2][3] += a.z * b.w;
            acc[3][0] += a.w * b.x; acc[3][1] += a.w * b.y; acc[3][2] += a.w * b.z; acc[3][3] += a.w * b.w;
        }
        __syncthreads();
    }

    // Epilogue: + bias, store (float4 per row)
    const float4 bv4 = *(const float4*)&bias[tx * 4];
    #pragma unroll
    for (int i = 0; i < 4; ++i) {
        float4 r4;
        r4.x = acc[i][0] + bv4.x;
        r4.y = acc[i][1] + bv4.y;
        r4.z = acc[i][2] + bv4.z;
        r4.w = acc[i][3] + bv4.w;
        *(float4*)(outp + (size_t)(m0 + ty * 4 + i) * Hd + tx * 4) = r4;
    }
}

// ---------------------------------------------------------------------------
// Kernel 2: flash attention (causal, online softmax), fp32.
// grid = (Seq/64, Bsz), block = 256.  One block = 64 query rows of one batch.
// ---------------------------------------------------------------------------
__global__ __launch_bounds__(256) void attn_kernel(
    const float* __restrict__ qkv,   // [3][Rows][Hd]
    float* __restrict__ out)         // [Bsz][Seq][Hd]
{
    const int b  = blockIdx.y;
    const int qt = blockIdx.x;       // 0..31
    const float* Q = qkv;
    const float* K = qkv + (size_t)Rows * Hd;
    const float* V = qkv + (size_t)2 * Rows * Hd;

    __shared__ float Qt_s[64][68];   // [d][q]  (transposed)
    __shared__ float Kt_s[64][68];   // [d][k]  (transposed)
    __shared__ float Vs[64][68];     // [k][d]
    __shared__ float Pt[64][68];     // [k][q]
    __shared__ float red[64][16];
    __shared__ float m_s[64], l_s[64], alpha_s[64];

    const int tid = threadIdx.x;
    const int tx  = tid % 16;        // second tile index (k for S, d for O)
    const int ty  = tid / 16;        // q tile index
    const int q0  = qt * 64;
    const size_t baseQ = ((size_t)b * Seq + q0) * Hd;

    // Load Q tile transposed: Qt_s[d][q]
    {
        const int r  = tid / 4;          // q row 0..63
        const int c0 = (tid % 4) * 16;   // d start
        #pragma unroll
        for (int cc = 0; cc < 16; cc += 4) {
            const float4 v = *(const float4*)(Q + baseQ + (size_t)r * Hd + c0 + cc);
            Qt_s[c0 + cc + 0][r] = v.x;
            Qt_s[c0 + cc + 1][r] = v.y;
            Qt_s[c0 + cc + 2][r] = v.z;
            Qt_s[c0 + cc + 3][r] = v.w;
        }
    }
    if (tid < 64) { m_s[tid] = -INFINITY; l_s[tid] = 0.0f; }

    float o[4][4] = {};
    __syncthreads();                               // Q / stats ready

    for (int kt = 0; kt <= qt; ++kt) {
        const int k0 = kt * 64;
        const size_t baseK = ((size_t)b * Seq + k0) * Hd;

        // Stage K (transposed) and V (straight)
        {
            const int r  = tid / 4;
            const int c0 = (tid % 4) * 16;
            #pragma unroll
            for (int cc = 0; cc < 16; cc += 4) {
                const float4 kv = *(const float4*)(K + baseK + (size_t)r * Hd + c0 + cc);
                Kt_s[c0 + cc + 0][r] = kv.x;
                Kt_s[c0 + cc + 1][r] = kv.y;
                Kt_s[c0 + cc + 2][r] = kv.z;
                Kt_s[c0 + cc + 3][r] = kv.w;
            }
            #pragma unroll
            for (int cc = 0; cc < 16; cc += 4) {
                *(float4*)&Vs[r][c0 + cc] =
                    *(const float4*)(V + baseK + (size_t)r * Hd + c0 + cc);
            }
        }
        __syncthreads();                           // (A) K/V staged

        // S = Q K^T  (4x4 per thread)
        float s[4][4] = {};
        #pragma unroll 8
        for (int d = 0; d < 64; ++d) {
            const float4 a  = *(const float4*)&Qt_s[d][ty * 4];
            const float4 bb = *(const float4*)&Kt_s[d][tx * 4];
            s[0][0] += a.x * bb.x; s[0][1] += a.x * bb.y; s[0][2] += a.x * bb.z; s[0][3] += a.x * bb.w;
            s[1][0] += a.y * bb.x; s[1][1] += a.y * bb.y; s[1][2] += a.y * bb.z; s[1][3] += a.y * bb.w;
            s[2][0] += a.z * bb.x; s[2][1] += a.z * bb.y; s[2][2] += a.z * bb.z; s[2][3] += a.z * bb.w;
            s[3][0] += a.w * bb.x; s[3][1] += a.w * bb.y; s[3][2] += a.w * bb.z; s[3][3] += a.w * bb.w;
        }

        // scale + causal mask + per-thread row max
        const float scale = 0.125f;   // 1/sqrt(64)
        float rmax[4];
        #pragma unroll
        for (int i = 0; i < 4; ++i) {
            rmax[i] = -INFINITY;
            const int qg = q0 + ty * 4 + i;
            #pragma unroll
            for (int j = 0; j < 4; ++j) {
                const int kg = k0 + tx * 4 + j;
                s[i][j] = (kg <= qg) ? s[i][j] * scale : -INFINITY;
                rmax[i] = fmaxf(rmax[i], s[i][j]);
            }
            red[ty * 4 + i][tx] = rmax[i];
        }
        __syncthreads();                           // (B) max partials ready

        if (tid < 64) {
            const float m_old = m_s[tid];
            float mt = red[tid][0];
            #pragma unroll
            for (int t = 1; t < 16; ++t) mt = fmaxf(mt, red[tid][t]);
            const float m_new = fmaxf(m_old, mt);
            m_s[tid]     = m_new;
            alpha_s[tid] = expf(m_old - m_new);    // exp(-inf)=0 on first tile
        }
        __syncthreads();                           // (C) m_new / alpha ready

        // P = exp(S - m_new); write Pt[k][q]; accumulate row sums
        #pragma unroll
        for (int i = 0; i < 4; ++i) {
            const float mn = m_s[ty * 4 + i];
            float rs = 0.0f;
            #pragma unroll
            for (int j = 0; j < 4; ++j) {
                s[i][j] = expf(s[i][j] - mn);      // masked -> exp(-inf)=0
                rs += s[i][j];
            }
            red[ty * 4 + i][tx] = rs;
        }
        #pragma unroll
        for (int j = 0; j < 4; ++j) {
            *(float4*)&Pt[tx * 4 + j][ty * 4] =
                make_float4(s[0][j], s[1][j], s[2][j], s[3][j]);
        }
        __syncthreads();                           // (D) P + sum partials ready

        if (tid < 64) {
            float ssum = red[tid][0];
            #pragma unroll
            for (int t = 1; t < 16; ++t) ssum += red[tid][t];
            l_s[tid] = l_s[tid] * alpha_s[tid] + ssum;
        }

        // Rescale O, then O += P V
        #pragma unroll
        for (int i = 0; i < 4; ++i) {
            const float a = alpha_s[ty * 4 + i];
            #pragma unroll
            for (int j = 0; j < 4; ++j) o[i][j] *= a;
        }
        #pragma unroll 8
        for (int k = 0; k < 64; ++k) {
            const float4 p = *(const float4*)&Pt[k][ty * 4];
            const float4 v = *(const float4*)&Vs[k][tx * 4];
            o[0][0] += p.x * v.x; o[0][1] += p.x * v.y; o[0][2] += p.x * v.z; o[0][3] += p.x * v.w;
            o[1][0] += p.y * v.x; o[1][1] += p.y * v.y; o[1][2] += p.y * v.z; o[1][3] += p.y * v.w;
            o[2][0] += p.z * v.x; o[2][1] += p.z * v.y; o[2][2] += p.z * v.z; o[2][3] += p.z * v.w;
            o[3][0] += p.w * v.x; o[3][1] += p.w * v.y; o[3][2] += p.w * v.z; o[3][3] += p.w * v.w;
        }
        __syncthreads();                           // (E) done with Kt/Vs/Pt
    }

    // Epilogue: O / l, store
    #pragma unroll
    for (int i = 0; i < 4; ++i) {
        const float inv = 1.0f / l_s[ty * 4 + i];
        float4 r4;
        r4.x = o[i][0] * inv;
        r4.y = o[i][1] * inv;
        r4.z = o[i][2] * inv;
        r4.w = o[i][3] * inv;
        *(float4*)(out + ((size_t)b * Seq + q0 + ty * 4 + i) * Hd + tx * 4) = r4;
    }
}

// ---------------------------------------------------------------------------
extern "C" void kernel_launch(void* const* d_in, const int* in_sizes, int n_in,
                              void* d_out, int out_size, void* d_ws, size_t ws_size,
                              hipStream_t stream)
{
    const float* x  = (const float*)d_in[0];
    const float* Wq = (const float*)d_in[1];
    const float* bq = (const float*)d_in[2];
    const float* Wk = (const float*)d_in[3];
    const float* bk = (const float*)d_in[4];
    const float* Wv = (const float*)d_in[5];
    const float* bv = (const float*)d_in[6];
    float* out = (float*)d_out;
    float* qkv = (float*)d_ws;   // [3][Rows][Hd] fp32 = 25.2 MB

    dim3 gridQKV(Rows / 64, 3);
    qkv_kernel<<<gridQKV, 256, 0, stream>>>(x, Wq, bq, Wk, bk, Wv, bv, qkv);

    dim3 gridAtt(Seq / 64, Bsz);
    attn_kernel<<<gridAtt, 256, 0, stream>>>(qkv, out);
}

// Round 2
// 392.667 us; speedup vs baseline: 1.4814x; 1.4814x over previous
//
#include <hip/hip_runtime.h>
#include <hip/hip_bf16.h>
#include <math.h>

// B=16, S=2048, D=1024, HD=64
constexpr int Bsz  = 16;
constexpr int Seq  = 2048;
constexpr int Din  = 1024;
constexpr int Hd   = 64;
constexpr int Rows = Bsz * Seq;   // 32768

typedef short  short8 __attribute__((ext_vector_type(8)));
typedef float  f32x4  __attribute__((ext_vector_type(4)));

__device__ __forceinline__ short bf16_bits(float f) {
    __hip_bfloat16 h = __float2bfloat16(f);   // RNE
    return __builtin_bit_cast(short, h);
}

// ---------------------------------------------------------------------------
// Prep: Wt[wgt][n][k] = bf16(W[k][n]).  grid 48 x 256.
// ---------------------------------------------------------------------------
__global__ __launch_bounds__(256) void wt_prep(
    const float* __restrict__ Wq, const float* __restrict__ Wk,
    const float* __restrict__ Wv, short* __restrict__ Wt)
{
    const int wgt = blockIdx.x >> 4;
    const int n0  = (blockIdx.x & 15) * 4;
    const float* W = (wgt == 0) ? Wq : (wgt == 1) ? Wk : Wv;
    short* o = Wt + (size_t)wgt * Hd * Din;
    #pragma unroll
    for (int i = 0; i < 16; ++i) {
        const int idx = i * 256 + threadIdx.x;      // 0..4095
        const int n = n0 + (idx >> 10);
        const int k = idx & 1023;
        o[(size_t)n * Din + k] = bf16_bits(W[(size_t)k * Hd + n]);
    }
}

// ---------------------------------------------------------------------------
// QKV projection, bf16 MFMA.  grid 512 x 256.  Block = 64 rows, all of Q,K,V.
// Writes Qb,Kb row-major bf16 and Vt[b][d][s] transposed bf16.
// ---------------------------------------------------------------------------
__global__ __launch_bounds__(256) void qkv_kernel(
    const float* __restrict__ x,
    const short* __restrict__ Wt,    // [3][64 n][1024 k]
    const float* __restrict__ bq, const float* __restrict__ bk,
    const float* __restrict__ bv,
    short* __restrict__ Qb, short* __restrict__ Kb, short* __restrict__ Vt)
{
    const int tid  = threadIdx.x;
    const int w    = tid >> 6;
    const int lane = tid & 63;
    const int quad = lane >> 4;
    const int l16  = lane & 15;
    const int m0   = blockIdx.x * 64;

    f32x4 acc[3][4] = {};   // [wgt][n-tile], C layout: row=quad*4+reg, col=nt*16+l16

    const float* xrow = x + (size_t)(m0 + w * 16 + l16) * Din + quad * 8;

    #pragma unroll 2
    for (int kk = 0; kk < Din; kk += 32) {
        const float4 a0 = *(const float4*)(xrow + kk);
        const float4 a1 = *(const float4*)(xrow + kk + 4);
        short8 af;
        af[0] = bf16_bits(a0.x); af[1] = bf16_bits(a0.y);
        af[2] = bf16_bits(a0.z); af[3] = bf16_bits(a0.w);
        af[4] = bf16_bits(a1.x); af[5] = bf16_bits(a1.y);
        af[6] = bf16_bits(a1.z); af[7] = bf16_bits(a1.w);
        #pragma unroll
        for (int wg = 0; wg < 3; ++wg) {
            #pragma unroll
            for (int nt = 0; nt < 4; ++nt) {
                const short8 bf = *(const short8*)(
                    Wt + ((size_t)wg * Hd + nt * 16 + l16) * Din + kk + quad * 8);
                acc[wg][nt] = __builtin_amdgcn_mfma_f32_16x16x32_bf16(
                    af, bf, acc[wg][nt], 0, 0, 0);
            }
        }
    }

    __shared__ __align__(16) short buf[64][72];
    const int b  = m0 / Seq;
    const int s0 = m0 % Seq;

    // Q then K: LDS transpose C-layout -> row-major, coalesced 16B stores
    #pragma unroll
    for (int wg = 0; wg < 2; ++wg) {
        const float* bias = (wg == 0) ? bq : bk;
        short* outp       = (wg == 0) ? Qb : Kb;
        #pragma unroll
        for (int nt = 0; nt < 4; ++nt) {
            const float bb = bias[nt * 16 + l16];
            #pragma unroll
            for (int r = 0; r < 4; ++r)
                buf[w * 16 + quad * 4 + r][nt * 16 + l16] = bf16_bits(acc[wg][nt][r] + bb);
        }
        __syncthreads();
        {
            const int rr = tid >> 2, c0 = (tid & 3) * 16;
            *(short8*)(outp + (size_t)(m0 + rr) * Hd + c0)     = *(const short8*)&buf[rr][c0];
            *(short8*)(outp + (size_t)(m0 + rr) * Hd + c0 + 8) = *(const short8*)&buf[rr][c0 + 8];
        }
        __syncthreads();
    }
    // V: transposed into buf[d][s_local], then coalesced along s
    #pragma unroll
    for (int nt = 0; nt < 4; ++nt) {
        const float bb = bv[nt * 16 + l16];
        #pragma unroll
        for (int r = 0; r < 4; ++r)
            buf[nt * 16 + l16][w * 16 + quad * 4 + r] = bf16_bits(acc[2][nt][r] + bb);
    }
    __syncthreads();
    {
        const int rr = tid >> 2, c0 = (tid & 3) * 16;  // rr = d, c0 = s offset
        *(short8*)(Vt + ((size_t)b * Hd + rr) * Seq + s0 + c0)     = *(const short8*)&buf[rr][c0];
        *(short8*)(Vt + ((size_t)b * Hd + rr) * Seq + s0 + c0 + 8) = *(const short8*)&buf[rr][c0 + 8];
    }
}

// ---------------------------------------------------------------------------
// Flash attention, bf16 MFMA, zero __syncthreads (per-wave-private LDS only).
// grid (32, 16) x 256.  Wave w owns q rows q0 + w*16 .. +15.
// ---------------------------------------------------------------------------
__global__ __launch_bounds__(256) void attn_kernel(
    const short* __restrict__ Qb, const short* __restrict__ Kb,
    const short* __restrict__ Vt, float* __restrict__ out)
{
    const int tid  = threadIdx.x;
    const int w    = tid >> 6;
    const int lane = tid & 63;
    const int quad = lane >> 4;
    const int l16  = lane & 15;
    const int b    = blockIdx.y;
    const int bx   = blockIdx.x;
    const int qt   = (bx & 1) ? (31 - (bx >> 1)) : (bx >> 1);  // load-balance remap
    const int q0   = qt * 64;

    __shared__ __align__(16) short Ps[4][16][72];   // per-wave P strip, A-layout rows

    // Q fragments (A operand), loaded once
    const size_t qbase = ((size_t)(b * Seq + q0 + w * 16 + l16)) * Hd + quad * 8;
    const short8 qf0 = *(const short8*)(Qb + qbase);
    const short8 qf1 = *(const short8*)(Qb + qbase + 32);

    f32x4 o0 = {}, o1 = {}, o2 = {}, o3 = {};
    float m_run[4], l_run[4];
    #pragma unroll
    for (int r = 0; r < 4; ++r) { m_run[r] = -INFINITY; l_run[r] = 0.0f; }

    const float C = 0.125f * 1.44269504088896340736f;  // scale * log2(e)

    for (int kt = 0; kt <= qt; ++kt) {
        const int k0 = kt * 64;

        // ---- S = Q K^T ----
        f32x4 s[4] = {};
        const size_t kbase = ((size_t)(b * Seq + k0 + l16)) * Hd + quad * 8;
        #pragma unroll
        for (int nt = 0; nt < 4; ++nt) {
            const short8 kf0 = *(const short8*)(Kb + kbase + (size_t)nt * 16 * Hd);
            const short8 kf1 = *(const short8*)(Kb + kbase + (size_t)nt * 16 * Hd + 32);
            s[nt] = __builtin_amdgcn_mfma_f32_16x16x32_bf16(qf0, kf0, s[nt], 0, 0, 0);
            s[nt] = __builtin_amdgcn_mfma_f32_16x16x32_bf16(qf1, kf1, s[nt], 0, 0, 0);
        }

        // ---- scale (+ causal mask only on the diagonal tile) ----
        if (kt == qt) {
            #pragma unroll
            for (int nt = 0; nt < 4; ++nt) {
                const int kg = nt * 16 + l16;
                #pragma unroll
                for (int r = 0; r < 4; ++r) {
                    const int qg = w * 16 + quad * 4 + r;
                    s[nt][r] = (kg <= qg) ? s[nt][r] * C : -INFINITY;
                }
            }
        } else {
            #pragma unroll
            for (int nt = 0; nt < 4; ++nt)
                #pragma unroll
                for (int r = 0; r < 4; ++r) s[nt][r] *= C;
        }

        // ---- online softmax (rows live inside one 16-lane quad) ----
        float rm[4];
        #pragma unroll
        for (int r = 0; r < 4; ++r)
            rm[r] = fmaxf(fmaxf(s[0][r], s[1][r]), fmaxf(s[2][r], s[3][r]));
        #pragma unroll
        for (int off = 1; off < 16; off <<= 1)
            #pragma unroll
            for (int r = 0; r < 4; ++r)
                rm[r] = fmaxf(rm[r], __shfl_xor(rm[r], off));

        float alpha[4];
        #pragma unroll
        for (int r = 0; r < 4; ++r) {
            const float mn = fmaxf(m_run[r], rm[r]);
            alpha[r] = exp2f(m_run[r] - mn);
            m_run[r] = mn;
        }

        float rs[4] = {0.f, 0.f, 0.f, 0.f};
        #pragma unroll
        for (int nt = 0; nt < 4; ++nt)
            #pragma unroll
            for (int r = 0; r < 4; ++r) {
                const float p = exp2f(s[nt][r] - m_run[r]);
                s[nt][r] = p;
                rs[r] += p;
            }
        #pragma unroll
        for (int off = 1; off < 16; off <<= 1)
            #pragma unroll
            for (int r = 0; r < 4; ++r)
                rs[r] += __shfl_xor(rs[r], off);
        #pragma unroll
        for (int r = 0; r < 4; ++r) l_run[r] = l_run[r] * alpha[r] + rs[r];

        // ---- rescale O ----
        #pragma unroll
        for (int r = 0; r < 4; ++r) {
            o0[r] *= alpha[r]; o1[r] *= alpha[r];
            o2[r] *= alpha[r]; o3[r] *= alpha[r];
        }

        // ---- P: C-layout -> A-layout via per-wave-private LDS ----
        #pragma unroll
        for (int nt = 0; nt < 4; ++nt)
            #pragma unroll
            for (int r = 0; r < 4; ++r)
                Ps[w][quad * 4 + r][nt * 16 + l16] = bf16_bits(s[nt][r]);

        const short8 pf0 = *(const short8*)&Ps[w][l16][quad * 8];
        const short8 pf1 = *(const short8*)&Ps[w][l16][32 + quad * 8];

        // ---- O += P V ----
        const size_t vbase = ((size_t)(b * Hd + l16)) * Seq + k0 + quad * 8;
        {
            const short8 vA = *(const short8*)(Vt + vbase);
            const short8 vB = *(const short8*)(Vt + vbase + 32);
            o0 = __builtin_amdgcn_mfma_f32_16x16x32_bf16(pf0, vA, o0, 0, 0, 0);
            o0 = __builtin_amdgcn_mfma_f32_16x16x32_bf16(pf1, vB, o0, 0, 0, 0);
        }
        {
            const short8 vA = *(const short8*)(Vt + vbase + (size_t)16 * Seq);
            const short8 vB = *(const short8*)(Vt + vbase + (size_t)16 * Seq + 32);
            o1 = __builtin_amdgcn_mfma_f32_16x16x32_bf16(pf0, vA, o1, 0, 0, 0);
            o1 = __builtin_amdgcn_mfma_f32_16x16x32_bf16(pf1, vB, o1, 0, 0, 0);
        }
        {
            const short8 vA = *(const short8*)(Vt + vbase + (size_t)32 * Seq);
            const short8 vB = *(const short8*)(Vt + vbase + (size_t)32 * Seq + 32);
            o2 = __builtin_amdgcn_mfma_f32_16x16x32_bf16(pf0, vA, o2, 0, 0, 0);
            o2 = __builtin_amdgcn_mfma_f32_16x16x32_bf16(pf1, vB, o2, 0, 0, 0);
        }
        {
            const short8 vA = *(const short8*)(Vt + vbase + (size_t)48 * Seq);
            const short8 vB = *(const short8*)(Vt + vbase + (size_t)48 * Seq + 32);
            o3 = __builtin_amdgcn_mfma_f32_16x16x32_bf16(pf0, vA, o3, 0, 0, 0);
            o3 = __builtin_amdgcn_mfma_f32_16x16x32_bf16(pf1, vB, o3, 0, 0, 0);
        }
    }

    // ---- epilogue: O / l ----
    float inv[4];
    #pragma unroll
    for (int r = 0; r < 4; ++r) inv[r] = 1.0f / l_run[r];
    const size_t obase = ((size_t)b * Seq + q0 + w * 16 + quad * 4) * Hd + l16;
    #pragma unroll
    for (int r = 0; r < 4; ++r) {
        out[obase + (size_t)r * Hd +  0] = o0[r] * inv[r];
        out[obase + (size_t)r * Hd + 16] = o1[r] * inv[r];
        out[obase + (size_t)r * Hd + 32] = o2[r] * inv[r];
        out[obase + (size_t)r * Hd + 48] = o3[r] * inv[r];
    }
}

// ---------------------------------------------------------------------------
extern "C" void kernel_launch(void* const* d_in, const int* in_sizes, int n_in,
                              void* d_out, int out_size, void* d_ws, size_t ws_size,
                              hipStream_t stream)
{
    const float* x  = (const float*)d_in[0];
    const float* Wq = (const float*)d_in[1];
    const float* bq = (const float*)d_in[2];
    const float* Wk = (const float*)d_in[3];
    const float* bk = (const float*)d_in[4];
    const float* Wv = (const float*)d_in[5];
    const float* bv = (const float*)d_in[6];
    float* out = (float*)d_out;

    short* Qb = (short*)d_ws;                   // [Rows][64] bf16, 4 MB
    short* Kb = Qb + (size_t)Rows * Hd;         // [Rows][64] bf16, 4 MB
    short* Vt = Kb + (size_t)Rows * Hd;         // [Bsz][64][Seq] bf16, 4 MB
    short* Wt = Vt + (size_t)Rows * Hd;         // [3][64][1024] bf16, 384 KB

    wt_prep<<<48, 256, 0, stream>>>(Wq, Wk, Wv, Wt);
    qkv_kernel<<<512, 256, 0, stream>>>(x, Wt, bq, bk, bv, Qb, Kb, Vt);
    attn_kernel<<<dim3(32, 16), 256, 0, stream>>>(Qb, Kb, Vt, out);
}

// Round 3
// 321.191 us; speedup vs baseline: 1.8111x; 1.2225x over previous
//
#include <hip/hip_runtime.h>
#include <hip/hip_bf16.h>
#include <math.h>

// B=16, S=2048, D=1024, HD=64
constexpr int Bsz  = 16;
constexpr int Seq  = 2048;
constexpr int Din  = 1024;
constexpr int Hd   = 64;
constexpr int Rows = Bsz * Seq;   // 32768

typedef short  short8 __attribute__((ext_vector_type(8)));
typedef short  sh4    __attribute__((ext_vector_type(4)));
typedef float  f32x4  __attribute__((ext_vector_type(4)));

__device__ __forceinline__ short bf16_bits(float f) {
    __hip_bfloat16 h = __float2bfloat16(f);   // RNE
    return __builtin_bit_cast(short, h);
}

// ---------------------------------------------------------------------------
// Wf fragment order: [chunk k/32][f = wg*4+nt][lane = quad*16+l16][j 0..8)
//   holds W_wg[k = chunk*32 + quad*8 + j][n = nt*16 + l16]
// 24576 units of 8 shorts.  grid 96 x 256.
// ---------------------------------------------------------------------------
__global__ __launch_bounds__(256) void wt_prep(
    const float* __restrict__ Wq, const float* __restrict__ Wk,
    const float* __restrict__ Wv, short* __restrict__ Wf)
{
    const int u     = blockIdx.x * 256 + threadIdx.x;   // 0..24575
    const int chunk = u / 768;
    const int rem   = u - chunk * 768;
    const int f     = rem >> 6;
    const int lane  = rem & 63;
    const int wg    = f >> 2, nt = f & 3;
    const int quad  = lane >> 4, l16 = lane & 15;
    const float* W  = (wg == 0) ? Wq : (wg == 1) ? Wk : Wv;
    const int k0 = chunk * 32 + quad * 8;
    const int n  = nt * 16 + l16;
    short8 v;
    #pragma unroll
    for (int j = 0; j < 8; ++j) v[j] = bf16_bits(W[(size_t)(k0 + j) * Hd + n]);
    *(short8*)(Wf + (size_t)u * 8) = v;
}

// ---------------------------------------------------------------------------
// QKV projection.  grid 512 x 512 threads (8 waves).
// wave = g*4 + w:  w = row-group (16 rows), g = n-group (6 frags of 12).
// Double-buffered LDS staging; fragment-ordered outputs Qf/Kf/Vf.
// ---------------------------------------------------------------------------
__global__ __launch_bounds__(512, 4) void qkv_kernel(
    const float* __restrict__ x,
    const short* __restrict__ Wf,
    const float* __restrict__ bq, const float* __restrict__ bk,
    const float* __restrict__ bv,
    short* __restrict__ Qf, short* __restrict__ Kf, short* __restrict__ Vf)
{
    const int tid  = threadIdx.x;
    const int wave = tid >> 6;        // 0..7
    const int lane = tid & 63;
    const int quad = lane >> 4;
    const int l16  = lane & 15;
    const int g    = wave >> 2;       // n-group: frags g*6 .. g*6+5
    const int w    = wave & 3;        // row-group: rows w*16 .. +15
    const int m0   = blockIdx.x * 64;

    __shared__ __align__(16) short Xs[2][64 * 40];   // bf16 x tile, 80B rows
    __shared__ __align__(16) short Bs[2][6144];      // 12 frags x 1KB
    __shared__ __align__(16) short epi[64 * 200];    // [row][col 0..191], pad
    __shared__ __align__(16) short epiV[64 * 80];    // [d][tok], pad

    // x staging assignment: thread -> (row, 4-float group)
    const int srow = tid >> 3;        // 0..63
    const int sgrp = tid & 7;         // 0..7
    const float* xsrc = x + (size_t)(m0 + srow) * Din + sgrp * 4;

    f32x4 acc[6] = {};

    auto stage = [&](int c, int bufi) {
        const float4 xv = *(const float4*)(xsrc + c * 32);
        const short* wsrc = Wf + (size_t)c * 6144 + wave * 512 + lane * 8;
        const short8 w0 = *(const short8*)wsrc;
        sh4 sv;
        sv[0] = bf16_bits(xv.x); sv[1] = bf16_bits(xv.y);
        sv[2] = bf16_bits(xv.z); sv[3] = bf16_bits(xv.w);
        *(sh4*)&Xs[bufi][srow * 40 + sgrp * 4] = sv;
        *(short8*)&Bs[bufi][wave * 512 + lane * 8] = w0;
        if (wave < 4) {
            const short8 w1 = *(const short8*)(wsrc + 4096);
            *(short8*)&Bs[bufi][(wave + 8) * 512 + lane * 8] = w1;
        }
    };

    stage(0, 0);
    __syncthreads();
    for (int c = 0; c < 32; ++c) {
        const int cur = c & 1;
        if (c + 1 < 32) stage(c + 1, cur ^ 1);
        const short8 a = *(const short8*)&Xs[cur][(w * 16 + l16) * 40 + quad * 8];
        #pragma unroll
        for (int fi = 0; fi < 6; ++fi) {
            const short8 bb = *(const short8*)&Bs[cur][(g * 6 + fi) * 512 + lane * 8];
            acc[fi] = __builtin_amdgcn_mfma_f32_16x16x32_bf16(a, bb, acc[fi], 0, 0, 0);
        }
        __syncthreads();
    }

    // ---- epilogue: bias, bf16, reorder to fragment-major layouts ----
    const float* bias_all[3] = {bq, bk, bv};
    #pragma unroll
    for (int fi = 0; fi < 6; ++fi) {
        const int f  = g * 6 + fi;
        const int wg = f >> 2, nt = f & 3;
        const float bb = bias_all[wg][nt * 16 + l16];
        #pragma unroll
        for (int r = 0; r < 4; ++r) {
            const short v = bf16_bits(acc[fi][r] + bb);
            const int row = w * 16 + quad * 4 + r;
            epi[row * 200 + wg * 64 + nt * 16 + l16] = v;
            if (wg == 2) epiV[(nt * 16 + l16) * 80 + row] = v;
        }
    }
    __syncthreads();
    {
        const int lane2 = tid & 63;
        const int q16 = lane2 & 15, q4 = lane2 >> 4;
        // Q: [tokgroup][dhalf][lane][8]
        {
            const int tg_l = tid >> 7, dh = (tid >> 6) & 1;
            const short8 v = *(const short8*)&epi[(tg_l * 16 + q16) * 200 + dh * 32 + q4 * 8];
            *(short8*)(Qf + (((size_t)(blockIdx.x * 4 + tg_l) * 2 + dh) * 64 + lane2) * 8) = v;
        }
        // K: [tile][dhalf][nt_tok][lane][8]   (B-operand: n=token, k=d)
        {
            const int dh = tid >> 8, nt = (tid >> 6) & 3;
            const short8 v = *(const short8*)&epi[(nt * 16 + q16) * 200 + 64 + dh * 32 + q4 * 8];
            *(short8*)(Kf + ((((size_t)blockIdx.x * 2 + dh) * 4 + nt) * 64 + lane2) * 8) = v;
        }
        // V: [tile][tokhalf][nt_d][lane][8]   (B-operand: n=d, k=token)
        {
            const int th = tid >> 8, nt = (tid >> 6) & 3;
            const short8 v = *(const short8*)&epiV[(nt * 16 + q16) * 80 + th * 32 + q4 * 8];
            *(short8*)(Vf + ((((size_t)blockIdx.x * 2 + th) * 4 + nt) * 64 + lane2) * 8) = v;
        }
    }
}

// ---------------------------------------------------------------------------
// Flash attention: zero __syncthreads, all fragment loads coalesced from
// fragment-ordered Qf/Kf/Vf (L2-hot).  grid (32,16) x 256.
// ---------------------------------------------------------------------------
__global__ __launch_bounds__(256) void attn_kernel(
    const short* __restrict__ Qf, const short* __restrict__ Kf,
    const short* __restrict__ Vf, float* __restrict__ out)
{
    const int tid  = threadIdx.x;
    const int wave = tid >> 6;
    const int lane = tid & 63;
    const int quad = lane >> 4;
    const int l16  = lane & 15;
    const int b    = blockIdx.y;
    const int bx   = blockIdx.x;
    const int qt   = (bx & 1) ? (31 - (bx >> 1)) : (bx >> 1);  // balance remap
    const int q0   = qt * 64;

    __shared__ __align__(16) short Ps[4][16 * 72];   // per-wave strip, 144B rows

    // Q fragments (A operand), loaded once, coalesced
    const int tgq = b * 128 + qt * 4 + wave;
    const short8 qf0 = *(const short8*)(Qf + ((size_t)tgq * 2 + 0) * 512 + lane * 8);
    const short8 qf1 = *(const short8*)(Qf + ((size_t)tgq * 2 + 1) * 512 + lane * 8);

    f32x4 o[4] = {};
    float m_run[4], l_run[4];
    #pragma unroll
    for (int r = 0; r < 4; ++r) { m_run[r] = -INFINITY; l_run[r] = 0.0f; }

    const float C = 0.125f * 1.44269504088896340736f;  // scale * log2(e)

    for (int kt = 0; kt <= qt; ++kt) {
        const short* ktile = Kf + (size_t)(b * 32 + kt) * 4096;
        const short* vtile = Vf + (size_t)(b * 32 + kt) * 4096;

        // ---- S = Q K^T ----
        f32x4 s[4] = {};
        #pragma unroll
        for (int nt = 0; nt < 4; ++nt) {
            const short8 kf0 = *(const short8*)(ktile + ((0 * 4 + nt) * 64 + lane) * 8);
            const short8 kf1 = *(const short8*)(ktile + ((1 * 4 + nt) * 64 + lane) * 8);
            s[nt] = __builtin_amdgcn_mfma_f32_16x16x32_bf16(qf0, kf0, s[nt], 0, 0, 0);
            s[nt] = __builtin_amdgcn_mfma_f32_16x16x32_bf16(qf1, kf1, s[nt], 0, 0, 0);
        }

        // ---- scale (+ causal mask only on diagonal tile) ----
        if (kt == qt) {
            #pragma unroll
            for (int nt = 0; nt < 4; ++nt) {
                const int kg = nt * 16 + l16;
                #pragma unroll
                for (int r = 0; r < 4; ++r) {
                    const int qg = wave * 16 + quad * 4 + r;
                    s[nt][r] = (kg <= qg) ? s[nt][r] * C : -INFINITY;
                }
            }
        } else {
            #pragma unroll
            for (int nt = 0; nt < 4; ++nt)
                #pragma unroll
                for (int r = 0; r < 4; ++r) s[nt][r] *= C;
        }

        // ---- online softmax (rows live inside one 16-lane group) ----
        float rm[4];
        #pragma unroll
        for (int r = 0; r < 4; ++r)
            rm[r] = fmaxf(fmaxf(s[0][r], s[1][r]), fmaxf(s[2][r], s[3][r]));
        #pragma unroll
        for (int off = 1; off < 16; off <<= 1)
            #pragma unroll
            for (int r = 0; r < 4; ++r)
                rm[r] = fmaxf(rm[r], __shfl_xor(rm[r], off));

        float alpha[4];
        #pragma unroll
        for (int r = 0; r < 4; ++r) {
            const float mn = fmaxf(m_run[r], rm[r]);
            alpha[r] = exp2f(m_run[r] - mn);
            m_run[r] = mn;
        }

        float rs[4] = {0.f, 0.f, 0.f, 0.f};
        #pragma unroll
        for (int nt = 0; nt < 4; ++nt)
            #pragma unroll
            for (int r = 0; r < 4; ++r) {
                const float p = exp2f(s[nt][r] - m_run[r]);
                s[nt][r] = p;
                rs[r] += p;
            }
        #pragma unroll
        for (int off = 1; off < 16; off <<= 1)
            #pragma unroll
            for (int r = 0; r < 4; ++r)
                rs[r] += __shfl_xor(rs[r], off);
        #pragma unroll
        for (int r = 0; r < 4; ++r) l_run[r] = l_run[r] * alpha[r] + rs[r];

        #pragma unroll
        for (int r = 0; r < 4; ++r) {
            o[0][r] *= alpha[r]; o[1][r] *= alpha[r];
            o[2][r] *= alpha[r]; o[3][r] *= alpha[r];
        }

        // ---- P: C-layout -> A-layout via per-wave-private LDS ----
        #pragma unroll
        for (int nt = 0; nt < 4; ++nt)
            #pragma unroll
            for (int r = 0; r < 4; ++r)
                Ps[wave][(quad * 4 + r) * 72 + nt * 16 + l16] = bf16_bits(s[nt][r]);

        const short8 pf0 = *(const short8*)&Ps[wave][l16 * 72 + quad * 8];
        const short8 pf1 = *(const short8*)&Ps[wave][l16 * 72 + 32 + quad * 8];

        // ---- O += P V ----
        #pragma unroll
        for (int nt = 0; nt < 4; ++nt) {
            const short8 vA = *(const short8*)(vtile + ((0 * 4 + nt) * 64 + lane) * 8);
            const short8 vB = *(const short8*)(vtile + ((1 * 4 + nt) * 64 + lane) * 8);
            o[nt] = __builtin_amdgcn_mfma_f32_16x16x32_bf16(pf0, vA, o[nt], 0, 0, 0);
            o[nt] = __builtin_amdgcn_mfma_f32_16x16x32_bf16(pf1, vB, o[nt], 0, 0, 0);
        }
    }

    // ---- epilogue: O / l ----
    float inv[4];
    #pragma unroll
    for (int r = 0; r < 4; ++r) inv[r] = 1.0f / l_run[r];
    const size_t obase = ((size_t)b * Seq + q0 + wave * 16 + quad * 4) * Hd + l16;
    #pragma unroll
    for (int r = 0; r < 4; ++r) {
        out[obase + (size_t)r * Hd +  0] = o[0][r] * inv[r];
        out[obase + (size_t)r * Hd + 16] = o[1][r] * inv[r];
        out[obase + (size_t)r * Hd + 32] = o[2][r] * inv[r];
        out[obase + (size_t)r * Hd + 48] = o[3][r] * inv[r];
    }
}

// ---------------------------------------------------------------------------
extern "C" void kernel_launch(void* const* d_in, const int* in_sizes, int n_in,
                              void* d_out, int out_size, void* d_ws, size_t ws_size,
                              hipStream_t stream)
{
    const float* x  = (const float*)d_in[0];
    const float* Wq = (const float*)d_in[1];
    const float* bq = (const float*)d_in[2];
    const float* Wk = (const float*)d_in[3];
    const float* bk = (const float*)d_in[4];
    const float* Wv = (const float*)d_in[5];
    const float* bv = (const float*)d_in[6];
    float* out = (float*)d_out;

    short* Qf = (short*)d_ws;                    // 2M shorts, 4 MB
    short* Kf = Qf + (size_t)Rows * Hd;          // 4 MB
    short* Vf = Kf + (size_t)Rows * Hd;          // 4 MB
    short* Wf = Vf + (size_t)Rows * Hd;          // 384 KB

    wt_prep<<<96, 256, 0, stream>>>(Wq, Wk, Wv, Wf);
    qkv_kernel<<<512, 512, 0, stream>>>(x, Wf, bq, bk, bv, Qf, Kf, Vf);
    attn_kernel<<<dim3(32, 16), 256, 0, stream>>>(Qf, Kf, Vf, out);
}

// Round 5
// 291.346 us; speedup vs baseline: 1.9966x; 1.1024x over previous
//
#include <hip/hip_runtime.h>
#include <hip/hip_bf16.h>
#include <math.h>

// B=16, S=2048, D=1024, HD=64
constexpr int Bsz  = 16;
constexpr int Seq  = 2048;
constexpr int Din  = 1024;
constexpr int Hd   = 64;
constexpr int Rows = Bsz * Seq;   // 32768

typedef short  short8 __attribute__((ext_vector_type(8)));
typedef float  f32x4  __attribute__((ext_vector_type(4)));

__device__ __forceinline__ short bf16_bits(float f) {
    __hip_bfloat16 h = __float2bfloat16(f);   // RNE
    return __builtin_bit_cast(short, h);
}

// ---------------------------------------------------------------------------
// Wf fragment order: [chunk k/32][f = wg*4+nt][lane = quad*16+l16][j 0..8)
//   holds W_wg[k = chunk*32 + quad*8 + j][n = nt*16 + l16]
// ---------------------------------------------------------------------------
__global__ __launch_bounds__(256) void wt_prep(
    const float* __restrict__ Wq, const float* __restrict__ Wk,
    const float* __restrict__ Wv, short* __restrict__ Wf)
{
    const int u     = blockIdx.x * 256 + threadIdx.x;   // 0..24575
    const int chunk = u / 768;
    const int rem   = u - chunk * 768;
    const int f     = rem >> 6;
    const int lane  = rem & 63;
    const int wg    = f >> 2, nt = f & 3;
    const int quad  = lane >> 4, l16 = lane & 15;
    const float* W  = (wg == 0) ? Wq : (wg == 1) ? Wk : Wv;
    const int k0 = chunk * 32 + quad * 8;
    const int n  = nt * 16 + l16;
    short8 v;
    #pragma unroll
    for (int j = 0; j < 8; ++j) v[j] = bf16_bits(W[(size_t)(k0 + j) * Hd + n]);
    *(short8*)(Wf + (size_t)u * 8) = v;
}

// ---------------------------------------------------------------------------
// QKV v5: barrier-free K-loop.  grid 512 x 256 (4 waves).
// Wave = 16 rows x all 12 fragments; x and Wf read directly from global.
// ---------------------------------------------------------------------------
__global__ __launch_bounds__(256) void qkv_kernel(
    const float* __restrict__ x,
    const short* __restrict__ Wf,
    const float* __restrict__ bq, const float* __restrict__ bk,
    const float* __restrict__ bv,
    short* __restrict__ Qf, short* __restrict__ Kf, short* __restrict__ Vf)
{
    const int tid  = threadIdx.x;
    const int wave = tid >> 6;
    const int lane = tid & 63;
    const int quad = lane >> 4;
    const int l16  = lane & 15;
    const int bx   = blockIdx.x;
    const int m0   = bx * 64;

    const float* xrow = x + (size_t)(m0 + wave * 16 + l16) * Din + quad * 8;

    f32x4 acc[12] = {};

    #pragma unroll 2
    for (int c = 0; c < 32; ++c) {
        const float4 a0 = *(const float4*)(xrow + c * 32);
        const float4 a1 = *(const float4*)(xrow + c * 32 + 4);
        short8 af;
        af[0] = bf16_bits(a0.x); af[1] = bf16_bits(a0.y);
        af[2] = bf16_bits(a0.z); af[3] = bf16_bits(a0.w);
        af[4] = bf16_bits(a1.x); af[5] = bf16_bits(a1.y);
        af[6] = bf16_bits(a1.z); af[7] = bf16_bits(a1.w);
        const short* wsrc = Wf + (size_t)c * 6144 + lane * 8;
        #pragma unroll
        for (int f = 0; f < 12; ++f) {
            const short8 bb = *(const short8*)(wsrc + f * 512);
            acc[f] = __builtin_amdgcn_mfma_f32_16x16x32_bf16(af, bb, acc[f], 0, 0, 0);
        }
    }

    // ---- epilogue ----
    // NOTE: strip row stride MUST be >= 64 shorts (cols nt*16+l16 span 0..63).
    __shared__ __align__(16) short eS[4][2][16 * 72];   // per-wave Q/K strips
    __shared__ __align__(16) short eV[64 * 80];         // block V: [d][tok]

    // Q (wg=0) and K (wg=1): per-wave C->A/B-layout transform, no barrier
    #pragma unroll
    for (int wg = 0; wg < 2; ++wg) {
        const float* bias = wg ? bk : bq;
        #pragma unroll
        for (int nt = 0; nt < 4; ++nt) {
            const float bb = bias[nt * 16 + l16];
            #pragma unroll
            for (int r = 0; r < 4; ++r)
                eS[wave][wg][(quad * 4 + r) * 72 + nt * 16 + l16] =
                    bf16_bits(acc[wg * 4 + nt][r] + bb);
        }
    }
    #pragma unroll
    for (int wg = 0; wg < 2; ++wg) {
        const short8 v0 = *(const short8*)&eS[wave][wg][l16 * 72 + quad * 8];
        const short8 v1 = *(const short8*)&eS[wave][wg][l16 * 72 + 32 + quad * 8];
        if (wg == 0) {
            const size_t tg = (size_t)bx * 4 + wave;
            *(short8*)(Qf + (tg * 2 + 0) * 512 + lane * 8) = v0;
            *(short8*)(Qf + (tg * 2 + 1) * 512 + lane * 8) = v1;
        } else {
            *(short8*)(Kf + (((size_t)bx * 2 + 0) * 4 + wave) * 512 + lane * 8) = v0;
            *(short8*)(Kf + (((size_t)bx * 2 + 1) * 4 + wave) * 512 + lane * 8) = v1;
        }
    }

    // V: block-shared transpose (one barrier), fragment-order store
    #pragma unroll
    for (int nt = 0; nt < 4; ++nt) {
        const float bb = bv[nt * 16 + l16];
        #pragma unroll
        for (int r = 0; r < 4; ++r)
            eV[(nt * 16 + l16) * 80 + wave * 16 + quad * 4 + r] =
                bf16_bits(acc[8 + nt][r] + bb);
    }
    __syncthreads();
    #pragma unroll
    for (int s = 0; s < 2; ++s) {
        const int slot   = tid + s * 256;
        const int lane_s = slot & 63;
        const int u      = slot >> 6;            // 0..7
        const int th     = u >> 2, ntd = u & 3;
        const int q_s    = lane_s >> 4, l_s = lane_s & 15;
        const short8 v = *(const short8*)&eV[(ntd * 16 + l_s) * 80 + th * 32 + q_s * 8];
        *(short8*)(Vf + (((size_t)bx * 2 + th) * 4 + ntd) * 512 + lane_s * 8) = v;
    }
}

// ---------------------------------------------------------------------------
// Flash attention v5: split-kt across 4 waves of one 16-row q strip + LDS
// merge.  grid (128, 16) x 256.  Loop is barrier-free (per-wave state).
// ---------------------------------------------------------------------------
__global__ __launch_bounds__(256) void attn_kernel(
    const short* __restrict__ Qf, const short* __restrict__ Kf,
    const short* __restrict__ Vf, float* __restrict__ out)
{
    const int tid  = threadIdx.x;
    const int wave = tid >> 6;
    const int lane = tid & 63;
    const int quad = lane >> 4;
    const int l16  = lane & 15;
    const int b    = blockIdx.y;
    const int bx   = blockIdx.x;
    const int qs   = (bx & 1) ? (127 - (bx >> 1)) : (bx >> 1);  // balance remap
    const int dTile = qs >> 2;
    const int tiles = dTile + 1;
    const int qoff  = (qs & 3) * 16;

    __shared__ __align__(16) unsigned char sm[17408 + 512];
    short* Ps   = (short*)sm;              // [4][16*72] per-wave strips (loop)
    float* Obuf = (float*)sm;              // [4][16][68]  (merge; aliases Ps)
    float* mb   = (float*)(sm + 17408);    // [4][16]
    float* lb   = mb + 64;                 // [4][16]

    // Q fragments, loaded once (coalesced)
    const size_t tg = (size_t)b * 128 + qs;
    const short8 qf0 = *(const short8*)(Qf + (tg * 2 + 0) * 512 + lane * 8);
    const short8 qf1 = *(const short8*)(Qf + (tg * 2 + 1) * 512 + lane * 8);

    f32x4 o[4] = {};
    float m_run[4], l_run[4];
    #pragma unroll
    for (int r = 0; r < 4; ++r) { m_run[r] = -INFINITY; l_run[r] = 0.0f; }

    const float C = 0.125f * 1.44269504088896340736f;  // scale * log2(e)

    for (int kt = wave; kt < tiles; kt += 4) {
        const short* ktile = Kf + (size_t)(b * 32 + kt) * 4096;
        const short* vtile = Vf + (size_t)(b * 32 + kt) * 4096;

        f32x4 s[4] = {};
        #pragma unroll
        for (int nt = 0; nt < 4; ++nt) {
            const short8 kf0 = *(const short8*)(ktile + ((0 * 4 + nt) * 64 + lane) * 8);
            const short8 kf1 = *(const short8*)(ktile + ((1 * 4 + nt) * 64 + lane) * 8);
            s[nt] = __builtin_amdgcn_mfma_f32_16x16x32_bf16(qf0, kf0, s[nt], 0, 0, 0);
            s[nt] = __builtin_amdgcn_mfma_f32_16x16x32_bf16(qf1, kf1, s[nt], 0, 0, 0);
        }

        if (kt == dTile) {
            #pragma unroll
            for (int nt = 0; nt < 4; ++nt) {
                const int kg = nt * 16 + l16;
                #pragma unroll
                for (int r = 0; r < 4; ++r) {
                    const int qg = qoff + quad * 4 + r;
                    s[nt][r] = (kg <= qg) ? s[nt][r] * C : -INFINITY;
                }
            }
        } else {
            #pragma unroll
            for (int nt = 0; nt < 4; ++nt)
                #pragma unroll
                for (int r = 0; r < 4; ++r) s[nt][r] *= C;
        }

        float rm[4];
        #pragma unroll
        for (int r = 0; r < 4; ++r)
            rm[r] = fmaxf(fmaxf(s[0][r], s[1][r]), fmaxf(s[2][r], s[3][r]));
        #pragma unroll
        for (int off = 1; off < 16; off <<= 1)
            #pragma unroll
            for (int r = 0; r < 4; ++r)
                rm[r] = fmaxf(rm[r], __shfl_xor(rm[r], off));

        float alpha[4];
        #pragma unroll
        for (int r = 0; r < 4; ++r) {
            const float mn = fmaxf(m_run[r], rm[r]);
            alpha[r] = exp2f(m_run[r] - mn);
            m_run[r] = mn;
        }

        float rs[4] = {0.f, 0.f, 0.f, 0.f};
        #pragma unroll
        for (int nt = 0; nt < 4; ++nt)
            #pragma unroll
            for (int r = 0; r < 4; ++r) {
                const float p = exp2f(s[nt][r] - m_run[r]);
                s[nt][r] = p;
                rs[r] += p;
            }
        #pragma unroll
        for (int off = 1; off < 16; off <<= 1)
            #pragma unroll
            for (int r = 0; r < 4; ++r)
                rs[r] += __shfl_xor(rs[r], off);
        #pragma unroll
        for (int r = 0; r < 4; ++r) l_run[r] = l_run[r] * alpha[r] + rs[r];

        #pragma unroll
        for (int r = 0; r < 4; ++r) {
            o[0][r] *= alpha[r]; o[1][r] *= alpha[r];
            o[2][r] *= alpha[r]; o[3][r] *= alpha[r];
        }

        // P: C-layout -> A-layout via per-wave-private strip (stride 72!)
        #pragma unroll
        for (int nt = 0; nt < 4; ++nt)
            #pragma unroll
            for (int r = 0; r < 4; ++r)
                Ps[wave * 1152 + (quad * 4 + r) * 72 + nt * 16 + l16] = bf16_bits(s[nt][r]);

        const short8 pf0 = *(const short8*)&Ps[wave * 1152 + l16 * 72 + quad * 8];
        const short8 pf1 = *(const short8*)&Ps[wave * 1152 + l16 * 72 + 32 + quad * 8];

        #pragma unroll
        for (int nt = 0; nt < 4; ++nt) {
            const short8 vA = *(const short8*)(vtile + ((0 * 4 + nt) * 64 + lane) * 8);
            const short8 vB = *(const short8*)(vtile + ((1 * 4 + nt) * 64 + lane) * 8);
            o[nt] = __builtin_amdgcn_mfma_f32_16x16x32_bf16(pf0, vA, o[nt], 0, 0, 0);
            o[nt] = __builtin_amdgcn_mfma_f32_16x16x32_bf16(pf1, vB, o[nt], 0, 0, 0);
        }
    }

    // ---- 4-wave merge ----
    if (l16 == 0) {
        #pragma unroll
        for (int r = 0; r < 4; ++r) mb[wave * 16 + quad * 4 + r] = m_run[r];
    }
    __syncthreads();   // all waves done with loop (Ps free); mb ready

    float fac[4];
    #pragma unroll
    for (int r = 0; r < 4; ++r) {
        const int row = quad * 4 + r;
        const float mg = fmaxf(fmaxf(mb[row], mb[16 + row]),
                               fmaxf(mb[32 + row], mb[48 + row]));
        fac[r] = exp2f(m_run[r] - mg);   // -inf -> 0 for idle waves
    }
    if (l16 == 0) {
        #pragma unroll
        for (int r = 0; r < 4; ++r) lb[wave * 16 + quad * 4 + r] = l_run[r] * fac[r];
    }
    #pragma unroll
    for (int nt = 0; nt < 4; ++nt)
        #pragma unroll
        for (int r = 0; r < 4; ++r)
            Obuf[wave * 1088 + (quad * 4 + r) * 68 + nt * 16 + l16] = o[nt][r] * fac[r];
    __syncthreads();

    // reduce 4 partials + store (coalesced float4)
    {
        const int row = tid >> 4;
        const int c0  = (tid & 15) * 4;
        const float lsum = lb[row] + lb[16 + row] + lb[32 + row] + lb[48 + row];
        float4 a = *(const float4*)&Obuf[0 * 1088 + row * 68 + c0];
        const float4 a1 = *(const float4*)&Obuf[1 * 1088 + row * 68 + c0];
        const float4 a2 = *(const float4*)&Obuf[2 * 1088 + row * 68 + c0];
        const float4 a3 = *(const float4*)&Obuf[3 * 1088 + row * 68 + c0];
        a.x += a1.x + a2.x + a3.x;  a.y += a1.y + a2.y + a3.y;
        a.z += a1.z + a2.z + a3.z;  a.w += a1.w + a2.w + a3.w;
        const float inv = 1.0f / lsum;
        float4 r4 = make_float4(a.x * inv, a.y * inv, a.z * inv, a.w * inv);
        *(float4*)(out + ((size_t)b * Seq + qs * 16 + row) * Hd + c0) = r4;
    }
}

// ---------------------------------------------------------------------------
extern "C" void kernel_launch(void* const* d_in, const int* in_sizes, int n_in,
                              void* d_out, int out_size, void* d_ws, size_t ws_size,
                              hipStream_t stream)
{
    const float* x  = (const float*)d_in[0];
    const float* Wq = (const float*)d_in[1];
    const float* bq = (const float*)d_in[2];
    const float* Wk = (const float*)d_in[3];
    const float* bk = (const float*)d_in[4];
    const float* Wv = (const float*)d_in[5];
    const float* bv = (const float*)d_in[6];
    float* out = (float*)d_out;

    short* Qf = (short*)d_ws;                    // 4 MB
    short* Kf = Qf + (size_t)Rows * Hd;          // 4 MB
    short* Vf = Kf + (size_t)Rows * Hd;          // 4 MB
    short* Wf = Vf + (size_t)Rows * Hd;          // 384 KB

    wt_prep<<<96, 256, 0, stream>>>(Wq, Wk, Wv, Wf);
    qkv_kernel<<<512, 256, 0, stream>>>(x, Wf, bq, bk, bv, Qf, Kf, Vf);
    attn_kernel<<<dim3(128, 16), 256, 0, stream>>>(Qf, Kf, Vf, out);
}